// Round 7
// baseline (37608.102 us; speedup 1.0000x reference)
//
#include <hip/hip_runtime.h>

// ----------------------------------------------------------------------------
// 2-layer LayerNorm-LSTM, SEQ=1024, B=64, IN=256, H=512.
// 64 persistent WGs: bid 0..31 = layer-0 team, 32..63 = layer-1 team.
// Each WG owns 16 hidden columns; weights fully LDS-resident; the 4 waves of
// a WG are independent 16-batch-row pipelines (no per-step barriers; gates
// live in MFMA D-registers).
// Cross-WG per step (agent scope, sc0+sc1):
//   * h exchange: TAG-VALIDATED f32 (|h|<1 -> bit30 free; tag=(t>>1)&1,
//     slot=t&1). BOUNDED optimistic poll (<=16 reload rounds), then FALLBACK
//     to the round-4/5-proven flag protocol (producer drains vmcnt + posts
//     per-wave flags after every publish). No unbounded data-spin -> no hang.
//   * LN stats: self-validating 8B entries, parity in signbit(sumsq)
//     (round-5-proven, 1 RT). Variance clamped >=0 (NaN hygiene).
//   * BP flag: L1 posts hA-read-complete for L0 overwrite backpressure.
// ----------------------------------------------------------------------------

typedef short  s16x8 __attribute__((ext_vector_type(8)));
typedef float  f32x4 __attribute__((ext_vector_type(4)));
typedef float  f32x2 __attribute__((ext_vector_type(2)));
typedef unsigned short u16;
typedef unsigned int   u32;
typedef unsigned long long u64;

constexpr int kSeq = 1024;

// ws layout (bytes)
constexpr size_t OF_FLAGS = 0;        // u32[384]: HFA[4][32] HFB[4][32] BP[4][32]
constexpr size_t OF_STAT0 = 2048;     // [64 rows][32 prod] f32x2 = 16384
constexpr size_t OF_STAT1 = 18432;    // 16384
constexpr size_t OF_HA    = 34816;    // f32 [2][64][512] = 262144 (bit30 = tag)
constexpr size_t OF_HB    = 296960;   // 262144
constexpr size_t OF_W0S   = 559104;   // 32*24*4*64*8 u16 = 3145728
constexpr size_t OF_W1S   = 3704832;  // 32*32*4*64*8 u16 = 4194304
constexpr size_t OF_XBF   = 7899136;  // 1024*64*256 u16 = 33554432
constexpr size_t WS_NEED  = OF_XBF + 33554432;

constexpr size_t OUT_HFIN = (size_t)kSeq * 64 * 512;
constexpr size_t OUT_CFIN = OUT_HFIN + 2 * 64 * 512;

__device__ __forceinline__ u16 f2bf(float f) {
  u32 u = __float_as_uint(f);
  return (u16)((u + 0x7fffu + ((u >> 16) & 1u)) >> 16);  // RNE; finite inputs
}

// ---------------- LLC-coherent (sc0 sc1) access helpers ---------------------
__device__ __forceinline__ void ldg16f_coh(f32x4& d, const void* p) {
  asm volatile("global_load_dwordx4 %0, %1, off sc0 sc1" : "=v"(d) : "v"(p) : "memory");
}
__device__ __forceinline__ void ldg8f_coh(f32x2& d, const void* p) {
  asm volatile("global_load_dwordx2 %0, %1, off sc0 sc1" : "=v"(d) : "v"(p) : "memory");
}
__device__ __forceinline__ void stg8_coh(float* p, float a, float b) {
  f32x2 t; t[0] = a; t[1] = b;
  asm volatile("global_store_dwordx2 %0, %1, off sc0 sc1" :: "v"(p), "v"(t) : "memory");
}
__device__ __forceinline__ void stg4_coh(float* p, u32 v) {
  asm volatile("global_store_dword %0, %1, off sc0 sc1" :: "v"(p), "v"(v) : "memory");
}
__device__ __forceinline__ void vm_wait() {
  asm volatile("s_waitcnt vmcnt(0)" ::: "memory");
  __builtin_amdgcn_sched_barrier(0);     // rule 18: nothing crosses the wait
}
// Spin until all 32 flags >= tgt (lanes read f[tid&31]); one wave calls.
__device__ __forceinline__ void waitge32(u32* f, u32 tgt) {
  const int l = threadIdx.x & 31;
  while (true) {
    u32 v = __hip_atomic_load(&f[l], __ATOMIC_RELAXED, __HIP_MEMORY_SCOPE_AGENT);
    if (__all((int)(v >= tgt))) break;
    __builtin_amdgcn_s_sleep(2);
  }
}

// always mask tag bit + pack 8 f32 -> bf16x8 fragment
__device__ __forceinline__ s16x8 frag_from(f32x4 a, f32x4 b) {
  #pragma unroll
  for (int e = 0; e < 4; ++e) {
    a[e] = __uint_as_float(__float_as_uint(a[e]) & 0xBFFFFFFFu);
    b[e] = __uint_as_float(__float_as_uint(b[e]) & 0xBFFFFFFFu);
  }
  union { u32 w[4]; s16x8 s; } r;
  asm("v_cvt_pk_bf16_f32 %0, %1, %2" : "=v"(r.w[0]) : "v"(a[0]), "v"(a[1]));
  asm("v_cvt_pk_bf16_f32 %0, %1, %2" : "=v"(r.w[1]) : "v"(a[2]), "v"(a[3]));
  asm("v_cvt_pk_bf16_f32 %0, %1, %2" : "=v"(r.w[2]) : "v"(b[0]), "v"(b[1]));
  asm("v_cvt_pk_bf16_f32 %0, %1, %2" : "=v"(r.w[3]) : "v"(b[2]), "v"(b[3]));
  return r.s;
}

// Bounded tag-validated acquire of a 16-row h panel; flag fallback (hang-proof)
__device__ __forceinline__ void acquire_h(
    f32x4 (&u)[16][2], const float* hrow, u32 wantT, u32* flagArr, u32 flagTgt)
{
  auto load_all = [&]() {
    #pragma unroll
    for (int kk = 0; kk < 16; ++kk) {
      ldg16f_coh(u[kk][0], hrow + kk * 32);
      ldg16f_coh(u[kk][1], hrow + kk * 32 + 4);
    }
  };
  load_all();
  int tries = 0; bool ok = false;
  while (true) {
    vm_wait();
    u32 bad = 0;
    #pragma unroll
    for (int kk = 0; kk < 16; ++kk)
      #pragma unroll
      for (int j = 0; j < 2; ++j)
        #pragma unroll
        for (int e = 0; e < 4; ++e)
          bad |= ((__float_as_uint(u[kk][j][e]) >> 30) ^ wantT) & 1u;
    if (__all((int)(bad == 0))) { ok = true; break; }
    if (++tries >= 16) break;                 // bounded: no data-spin hang
    __builtin_amdgcn_s_sleep(1);
    load_all();
  }
  if (!ok) {                                  // proven flag protocol
    waitge32(flagArr, flagTgt);
    load_all();
    vm_wait();
  }
}

// ---------------------------------------------------------------- conversions
__global__ void conv_x_k(const float* __restrict__ x, u16* __restrict__ xd, size_t n) {
  size_t i = (size_t)blockIdx.x * blockDim.x + threadIdx.x;
  size_t st = (size_t)gridDim.x * blockDim.x;
  for (; i < n; i += st) xd[i] = f2bf(x[i]);
}

// W [2048][Kdim] -> [ns(32)][kst(KST)][nt(4)][lane(64)][e(8)]
__global__ void conv_w_k(const float* __restrict__ W, u16* __restrict__ Wd,
                         int KST, int Kdim) {
  int i = blockIdx.x * blockDim.x + threadIdx.x;
  if (i >= 32 * KST * 2048) return;
  int e = i & 7, lane = (i >> 3) & 63, nt = (i >> 9) & 3;
  int r = i >> 11;
  int kst = r % KST, ns = r / KST;
  int n_orig = nt * 512 + ns * 16 + (lane & 15);
  int k = kst * 32 + ((lane >> 4) << 3) + e;
  Wd[i] = f2bf(W[(size_t)n_orig * Kdim + k]);
}

__global__ void init_k(char* ws, const float* __restrict__ h0) {
  int i = blockIdx.x * blockDim.x + threadIdx.x;   // 0..32767
  u32* f = (u32*)ws;
  if (i < 384) f[i] = 0u;
  if (i < 2048) {   // stats: sign(q)=1 != (t=0)&1 -> invalid for step 0
    ((u64*)(ws + OF_STAT0))[i] = 0x8000000000000000ull;
    ((u64*)(ws + OF_STAT1))[i] = 0x8000000000000000ull;
  }
  float* hAf = (float*)(ws + OF_HA);
  float* hBf = (float*)(ws + OF_HB);
  // slot 1 (t=-1): h0 tagged 1; slot 0: dummy tag=1 (rejects t=0 reads; also
  // defeats 0xAA poison whose bit30==0).
  u32 bA = (__float_as_uint(h0[i])         & 0xBFFFFFFFu) | 0x40000000u;
  u32 bB = (__float_as_uint(h0[32768 + i]) & 0xBFFFFFFFu) | 0x40000000u;
  hAf[32768 + i] = __uint_as_float(bA);
  hBf[32768 + i] = __uint_as_float(bB);
  hAf[i] = __uint_as_float(0x40000000u);
  hBf[i] = __uint_as_float(0x40000000u);
}

// ---------------------------------------------------------------- team loop
template <int ROLE>
__device__ __forceinline__ void team_loop(
    int ns, char* smem,
    const u16* __restrict__ xbf, const u16* __restrict__ wsw,
    float* hAf, float* hBf, float* statT,
    u32* HFA, u32* HFB, u32* BP,
    const float* __restrict__ bias, const float* __restrict__ gam_,
    const float* __restrict__ bet_, const float* __restrict__ c0in,
    float* __restrict__ out)
{
  constexpr int KST = ROLE ? 32 : 24;     // K/32
  const int tid = threadIdx.x;
  const int lane = tid & 63, wid = tid >> 6;
  const int arow = wid * 16 + (lane & 15);          // batch row of A-frag
  const int acol = (lane >> 4) << 3;                // k offset within 32
  const int colL = lane & 15;                       // owned col within 16
  const int jgl  = ns * 16 + colL;                  // owned hidden column
  const int rbase = wid * 16 + ((lane >> 4) << 2);  // first of 4 owned rows

  u32* HF = ROLE ? HFB : HFA;

  s16x8* wl  = (s16x8*)smem;                        // KST*4 KB weights
  float* mus = (float*)(smem + (size_t)KST * 4096); // [64][2]

  // weights fully into LDS (only barrier in the kernel)
  const s16x8* wsrc = (const s16x8*)wsw + (size_t)ns * KST * 256;
  for (int i = tid; i < KST * 256; i += 256) wl[i] = wsrc[i];

  const float bi = bias[jgl], bf_ = bias[512 + jgl];
  const float bo = bias[1024 + jgl], bc = bias[1536 + jgl];
  const float gm = gam_[jgl], bt = bet_[jgl];
  float cst[4];
  #pragma unroll
  for (int k = 0; k < 4; ++k)
    cst[k] = c0in[(size_t)(ROLE * 64 + rbase + k) * 512 + jgl];
  __syncthreads();

  for (int t = 0; t < kSeq; ++t) {
    const u32 tagPub = ((u32)t >> 1) & 1;
    if (ROLE == 0 && t >= 2) waitge32(BP + wid * 32, (u32)(t - 1));  // backpressure

    f32x4 acc[4];
    #pragma unroll
    for (int nt = 0; nt < 4; ++nt) acc[nt] = (f32x4){0.f, 0.f, 0.f, 0.f};
    f32x4 u[16][2];

    if (ROLE == 0) {
      s16x8 xp[8];
      const u16* xr = xbf + ((size_t)t * 64 + arow) * 256 + acol;
      #pragma unroll
      for (int kk = 0; kk < 8; ++kk) xp[kk] = *(const s16x8*)(xr + kk * 32);
      #pragma unroll
      for (int kk = 0; kk < 8; ++kk)
        #pragma unroll
        for (int nt = 0; nt < 4; ++nt)
          acc[nt] = __builtin_amdgcn_mfma_f32_16x16x32_bf16(
              xp[kk], wl[(kk * 4 + nt) * 64 + lane], acc[nt], 0, 0, 0);
      // hA(t-1): slot (t-1)&1 == (t+1)&1
      acquire_h(u, hAf + (size_t)((t + 1) & 1) * 32768 + (size_t)arow * 512 + acol,
                ((u32)(t - 1) >> 1) & 1, HFA + wid * 32, (u32)t);
      #pragma unroll
      for (int kk = 0; kk < 16; ++kk) {
        s16x8 af = frag_from(u[kk][0], u[kk][1]);
        #pragma unroll
        for (int nt = 0; nt < 4; ++nt)
          acc[nt] = __builtin_amdgcn_mfma_f32_16x16x32_bf16(
              af, wl[((8 + kk) * 4 + nt) * 64 + lane], acc[nt], 0, 0, 0);
      }
    } else {
      // hB(t-1), own team (usually already valid)
      acquire_h(u, hBf + (size_t)((t + 1) & 1) * 32768 + (size_t)arow * 512 + acol,
                ((u32)(t - 1) >> 1) & 1, HFB + wid * 32, (u32)t);
      #pragma unroll
      for (int kk = 0; kk < 16; ++kk) {
        s16x8 af = frag_from(u[kk][0], u[kk][1]);
        #pragma unroll
        for (int nt = 0; nt < 4; ++nt)
          acc[nt] = __builtin_amdgcn_mfma_f32_16x16x32_bf16(
              af, wl[((16 + kk) * 4 + nt) * 64 + lane], acc[nt], 0, 0, 0);
      }
      // hA(t), fresh from layer 0 (the real wait)
      acquire_h(u, hAf + (size_t)(t & 1) * 32768 + (size_t)arow * 512 + acol,
                ((u32)t >> 1) & 1, HFA + wid * 32, (u32)(t + 1));
      if (lane == 0)
        __hip_atomic_store(&BP[wid * 32 + ns], (u32)(t + 1),
                           __ATOMIC_RELAXED, __HIP_MEMORY_SCOPE_AGENT);
      #pragma unroll
      for (int kk = 0; kk < 16; ++kk) {
        s16x8 af = frag_from(u[kk][0], u[kk][1]);
        #pragma unroll
        for (int nt = 0; nt < 4; ++nt)
          acc[nt] = __builtin_amdgcn_mfma_f32_16x16x32_bf16(
              af, wl[(kk * 4 + nt) * 64 + lane], acc[nt], 0, 0, 0);
      }
    }

    // ---------------- elementwise: 4 cells/lane, gates direct from acc [m89]
    float oo[4], sv[4], qv[4];
    #pragma unroll
    for (int k = 0; k < 4; ++k) {
      const float gi = acc[0][k] + bi;
      const float gf = acc[1][k] + bf_;
      const float go = acc[2][k] + bo;
      const float gc = acc[3][k] + bc;
      const float iv = 1.f / (1.f + __expf(-gi));
      const float fv = 1.f / (1.f + __expf(-gf));
      oo[k] = 1.f / (1.f + __expf(-go));
      const float cn = iv * tanhf(gc) + fv * cst[k];
      cst[k] = cn;
      sv[k] = cn; qv[k] = cn * cn;
    }
    #pragma unroll
    for (int m = 1; m <= 8; m <<= 1)
      #pragma unroll
      for (int k = 0; k < 4; ++k) { sv[k] += __shfl_xor(sv[k], m); qv[k] += __shfl_xor(qv[k], m); }
    if (colL == 0) {
      #pragma unroll
      for (int k = 0; k < 4; ++k) {
        const float qs = (t & 1) ? -qv[k] : qv[k];      // parity in signbit
        stg8_coh(statT + ((size_t)(rbase + k) * 32 + ns) * 2, sv[k], qs);
      }
    }

    // ---------------- stats poll (self-validating, 1 RT); wave-local rows
    {
      const int prow = wid * 16 + (lane >> 2);
      const float* pb = statT + ((size_t)prow * 32 + (size_t)(lane & 3) * 8) * 2;
      const u32 want = (u32)(t & 1);
      f32x2 e[8];
      while (true) {
        #pragma unroll
        for (int j = 0; j < 8; ++j) ldg8f_coh(e[j], pb + j * 2);
        vm_wait();
        u32 ok = 1;
        #pragma unroll
        for (int j = 0; j < 8; ++j) ok &= ((__float_as_uint(e[j][1]) >> 31) == want);
        if (__all((int)ok)) break;
        __builtin_amdgcn_s_sleep(1);
      }
      float ss = 0.f, qq = 0.f;
      #pragma unroll
      for (int j = 0; j < 8; ++j) { ss += e[j][0]; qq += __builtin_fabsf(e[j][1]); }
      ss += __shfl_xor(ss, 1); qq += __shfl_xor(qq, 1);
      ss += __shfl_xor(ss, 2); qq += __shfl_xor(qq, 2);
      if ((lane & 3) == 0) {
        const float mu = ss * (1.f / 512.f);
        const float ms = qq * (1.f / 512.f);
        mus[prow * 2]     = mu;
        mus[prow * 2 + 1] = rsqrtf(fmaxf(ms - mu * mu, 0.f) + 1e-5f);  // NaN hygiene
      }
    }

    // ---------------- h publish (tagged f32), drain + flag (fallback insurance)
    float* hdst = (ROLE ? hBf : hAf) + (size_t)(t & 1) * 32768;
    float hvv[4];
    #pragma unroll
    for (int k = 0; k < 4; ++k) {
      const int row = rbase + k;
      const float mu = mus[row * 2], rs = mus[row * 2 + 1];
      const float hv = oo[k] * tanhf((cst[k] - mu) * rs * gm + bt);
      hvv[k] = hv;
      stg4_coh(hdst + (size_t)row * 512 + jgl,
               (__float_as_uint(hv) & 0xBFFFFFFFu) | (tagPub << 30));
    }
    if (ROLE == 1) {
      #pragma unroll
      for (int k = 0; k < 4; ++k)
        out[((size_t)t * 64 + rbase + k) * 512 + jgl] = hvv[k];
    }
    if (t == kSeq - 1) {
      #pragma unroll
      for (int k = 0; k < 4; ++k) {
        out[OUT_HFIN + (size_t)ROLE * 32768 + (size_t)(rbase + k) * 512 + jgl] = hvv[k];
        out[OUT_CFIN + (size_t)ROLE * 32768 + (size_t)(rbase + k) * 512 + jgl] = cst[k];
      }
    }
    vm_wait();
    if (lane == 0)
      __hip_atomic_store(&HF[wid * 32 + ns], (u32)(t + 1),
                         __ATOMIC_RELAXED, __HIP_MEMORY_SCOPE_AGENT);
  }
}

// ---------------------------------------------------------------- persistent
__global__ __launch_bounds__(256, 1) void lstm_persist(
    const u16* __restrict__ xbf, const u16* __restrict__ w0s, const u16* __restrict__ w1s,
    char* ws,
    const float* __restrict__ b0, const float* __restrict__ lg0, const float* __restrict__ lb0,
    const float* __restrict__ b1, const float* __restrict__ lg1, const float* __restrict__ lb1,
    const float* __restrict__ c0in, float* __restrict__ out)
{
  extern __shared__ char smem[];
  const int bid = blockIdx.x;
  u32* HFA = (u32*)(ws + OF_FLAGS);
  u32* HFB = HFA + 128;
  u32* BP  = HFA + 256;
  float* hAf = (float*)(ws + OF_HA);
  float* hBf = (float*)(ws + OF_HB);
  float* st0 = (float*)(ws + OF_STAT0);
  float* st1 = (float*)(ws + OF_STAT1);

  if (bid < 32)
    team_loop<0>(bid, smem, xbf, w0s, hAf, hBf, st0, HFA, HFB, BP,
                 b0, lg0, lb0, c0in, out);
  else
    team_loop<1>(bid - 32, smem, xbf, w1s, hAf, hBf, st1, HFA, HFB, BP,
                 b1, lg1, lb1, c0in, out);
}

// ---------------------------------------------------------------- launch
extern "C" void kernel_launch(void* const* d_in, const int* in_sizes, int n_in,
                              void* d_out, int out_size, void* d_ws, size_t ws_size,
                              hipStream_t stream) {
  (void)in_sizes; (void)n_in; (void)out_size;
  const float* x   = (const float*)d_in[0];
  const float* h0  = (const float*)d_in[1];
  const float* c0  = (const float*)d_in[2];
  const float* W0  = (const float*)d_in[3];
  const float* b0  = (const float*)d_in[4];
  const float* g0  = (const float*)d_in[5];
  const float* be0 = (const float*)d_in[6];
  const float* W1  = (const float*)d_in[7];
  const float* b1  = (const float*)d_in[8];
  const float* g1  = (const float*)d_in[9];
  const float* be1 = (const float*)d_in[10];
  float* out = (float*)d_out;

  if (ws_size < WS_NEED) return;   // fail loudly (output stays poisoned)

  char* ws = (char*)d_ws;
  u16* w0s = (u16*)(ws + OF_W0S);
  u16* w1s = (u16*)(ws + OF_W1S);
  u16* xbf = (u16*)(ws + OF_XBF);

  hipLaunchKernelGGL(conv_x_k, dim3(2048), dim3(256), 0, stream,
                     x, xbf, (size_t)kSeq * 64 * 256);
  hipLaunchKernelGGL(conv_w_k, dim3(6144), dim3(256), 0, stream, W0, w0s, 24, 768);
  hipLaunchKernelGGL(conv_w_k, dim3(8192), dim3(256), 0, stream, W1, w1s, 32, 1024);
  hipLaunchKernelGGL(init_k,   dim3(128),  dim3(256), 0, stream, ws, h0);
  hipLaunchKernelGGL(lstm_persist, dim3(64), dim3(256), 131584, stream,
                     xbf, w0s, w1s, ws,
                     b0, g0, be0, b1, g1, be1, c0, out);
}

// Round 12
// 16283.147 us; speedup vs baseline: 2.3096x; 2.3096x over previous
//
#include <hip/hip_runtime.h>

// ----------------------------------------------------------------------------
// 2-layer LayerNorm-LSTM, SEQ=1024, B=64, IN=256, H=512.
// 64 persistent WGs: bid 0..31 = layer-0 team, 32..63 = layer-1 team.
// Each WG owns 16 hidden columns (all 4 gates), weights fully LDS-resident,
// fused matmul (bf16 MFMA) + elementwise + LN, cell state in registers.
// Sync protocol = ROUND-5-PROVEN, byte-identical: h via sc0sc1 loads +
// dense u32 flags; LN stats via self-validating 8B entries (parity in
// signbit of sum-of-squares, 1 RT).
// R12 change vs R5 (data path only): h-publish is coalesced — h tile staged
// in LDS [64][16] u16, then ONE aligned 8B sc0sc1 store per thread (256/WG)
// instead of 1024 scattered 2B stores; out[]/final writes deferred until
// after the flag post so they leave the vmcnt(0) drain window.
// ----------------------------------------------------------------------------

typedef short  s16x8 __attribute__((ext_vector_type(8)));
typedef float  f32x4 __attribute__((ext_vector_type(4)));
typedef float  f32x2 __attribute__((ext_vector_type(2)));
typedef unsigned short u16;
typedef unsigned int   u32;
typedef unsigned long long u64;

constexpr int kSeq = 1024;

// ws layout (bytes)
constexpr size_t OF_FLAGS = 0;            // u32[64]: HFA[32] HF1[32]
constexpr size_t OF_STAT0 = 1024;         // [64 rows][32 prod] float2 = 16384
constexpr size_t OF_STAT1 = 17408;        // 16384
constexpr size_t OF_HA    = 33792;        // [2 parity][64][512] u16 = 131072
constexpr size_t OF_HB    = 164864;       // 131072
constexpr size_t OF_W0S   = 295936;       // 32*24*4*64*8 u16 = 3145728
constexpr size_t OF_W1S   = 3441664;      // 32*32*4*64*8 u16 = 4194304
constexpr size_t OF_XBF   = 7635968;      // 1024*64*256 u16 = 33554432
constexpr size_t WS_NEED  = OF_XBF + 33554432;

constexpr size_t OUT_HFIN = (size_t)kSeq * 64 * 512;
constexpr size_t OUT_CFIN = OUT_HFIN + 2 * 64 * 512;

__device__ __forceinline__ u16 f2bf(float f) {
  u32 u = __float_as_uint(f);
  return (u16)((u + 0x7fffu + ((u >> 16) & 1u)) >> 16);  // RNE; finite inputs
}

// ---------------- LLC-coherent (sc0 sc1) access helpers ---------------------
__device__ __forceinline__ void ldg16_coh(s16x8& d, const void* p) {
  asm volatile("global_load_dwordx4 %0, %1, off sc0 sc1" : "=v"(d) : "v"(p) : "memory");
}
__device__ __forceinline__ void ldg8f_coh(f32x2& d, const void* p) {
  asm volatile("global_load_dwordx2 %0, %1, off sc0 sc1" : "=v"(d) : "v"(p) : "memory");
}
__device__ __forceinline__ void stg8_coh(float* p, float a, float b) {
  f32x2 t; t[0] = a; t[1] = b;
  asm volatile("global_store_dwordx2 %0, %1, off sc0 sc1" :: "v"(p), "v"(t) : "memory");
}
__device__ __forceinline__ void stg8u_coh(u16* p, u64 v) {
  asm volatile("global_store_dwordx2 %0, %1, off sc0 sc1" :: "v"(p), "v"(v) : "memory");
}
__device__ __forceinline__ void vm_wait() {
  asm volatile("s_waitcnt vmcnt(0)" ::: "memory");
  __builtin_amdgcn_sched_barrier(0);     // rule 18: nothing crosses the wait
}
// Spin until all 32 flags >= tgt (all 64 lanes read flags[lane&31]).
__device__ __forceinline__ void waitge(u32* f, u32 tgt) {
  const int l = threadIdx.x & 31;
  while (true) {
    u32 v = __hip_atomic_load(&f[l], __ATOMIC_RELAXED, __HIP_MEMORY_SCOPE_AGENT);
    if (__all((int)(v >= tgt))) break;
    __builtin_amdgcn_s_sleep(2);
  }
}

// ---------------------------------------------------------------- conversions
__global__ void conv_x_k(const float* __restrict__ x, u16* __restrict__ xd, size_t n) {
  size_t i = (size_t)blockIdx.x * blockDim.x + threadIdx.x;
  size_t st = (size_t)gridDim.x * blockDim.x;
  for (; i < n; i += st) xd[i] = f2bf(x[i]);
}

// W [2048][Kdim] -> [ns(32)][kst(KST)][nt(4)][lane(64)][e(8)]
// n_orig = nt*512 + ns*16 + (lane&15); k = kst*32 + (lane>>4)*8 + e
__global__ void conv_w_k(const float* __restrict__ W, u16* __restrict__ Wd,
                         int KST, int Kdim) {
  int i = blockIdx.x * blockDim.x + threadIdx.x;
  if (i >= 32 * KST * 2048) return;
  int e = i & 7, lane = (i >> 3) & 63, nt = (i >> 9) & 3;
  int r = i >> 11;
  int kst = r % KST, ns = r / KST;
  int n_orig = nt * 512 + ns * 16 + (lane & 15);
  int k = kst * 32 + ((lane >> 4) << 3) + e;
  Wd[i] = f2bf(W[(size_t)n_orig * Kdim + k]);
}

__global__ void init_k(char* ws, const float* __restrict__ h0) {
  int i = blockIdx.x * blockDim.x + threadIdx.x;   // 0..32767
  u32* f = (u32*)ws;
  if (i < 64) f[i] = 0u;
  if (i < 4096) {       // stats entries -> (s=0, q=-0.0): signbit 1 != (t=0)&1
    ((u64*)(ws + OF_STAT0))[i] = 0x8000000000000000ull;
    ((u64*)(ws + OF_STAT1))[i] = 0x8000000000000000ull;
  }
  // parity-1 buffers <- initial hidden states
  ((u16*)(ws + OF_HA))[32768 + i] = f2bf(h0[i]);
  ((u16*)(ws + OF_HB))[32768 + i] = f2bf(h0[32768 + i]);
}

// ---------------------------------------------------------------- team loop
template <int ROLE>
__device__ __forceinline__ void team_loop(
    int ns, char* smem,
    const u16* __restrict__ xbf, const u16* __restrict__ wsw,
    u16* hA, u16* hB, float* statT, u32* flags,
    const float* __restrict__ bias, const float* __restrict__ gam_,
    const float* __restrict__ bet_, const float* __restrict__ c0in,
    float* __restrict__ out)
{
  constexpr int KST = ROLE ? 32 : 24;     // K/32
  const int tid = threadIdx.x;
  const int lane = tid & 63, wid = tid >> 6;
  const int arow = wid * 16 + (lane & 15);        // batch row of A-frag
  const int acol = (lane >> 4) << 3;              // K offset within 32
  const int jl = tid & 15, rg = tid >> 4;         // EW col-in-16, row-group
  const int jg = ns * 16 + jl;                    // owned hidden column

  u32* HFA = flags;
  u32* HF1 = flags + 32;
  u32* HF  = ROLE ? HF1 : HFA;

  s16x8* wl    = (s16x8*)smem;                    // KST*4 KB weights
  float* gates = (float*)(smem + (size_t)KST * 4096);          // [4][64][17] f32
  float* mus   = (float*)(smem + (size_t)KST * 4096 + 17408);  // [64][2]
  u16*   hst   = (u16*)(smem + (size_t)KST * 4096 + 17920);    // [64][16] u16

  // weights fully into LDS
  const s16x8* wsrc = (const s16x8*)wsw + (size_t)ns * KST * 256;
  for (int i = tid; i < KST * 256; i += 256) wl[i] = wsrc[i];

  const float bi = bias[jg], bf_ = bias[512 + jg], bo = bias[1024 + jg], bc = bias[1536 + jg];
  const float gm = gam_[jg], bt = bet_[jg];
  float cst[4];
  #pragma unroll
  for (int k = 0; k < 4; ++k)
    cst[k] = c0in[(size_t)(ROLE * 64 + rg * 4 + k) * 512 + jg];
  __syncthreads();

  for (int t = 0; t < kSeq; ++t) {
    f32x4 acc[4];
    #pragma unroll
    for (int nt = 0; nt < 4; ++nt) acc[nt] = (f32x4){0.f, 0.f, 0.f, 0.f};

    // ------------- matmul: gates[64b][64 gatecols] = act(t) @ W^T
    if (ROLE == 0) {
      s16x8 xp[8];
      const u16* xr = xbf + ((size_t)t * 64 + arow) * 256 + acol;
      #pragma unroll
      for (int kk = 0; kk < 8; ++kk) xp[kk] = *(const s16x8*)(xr + kk * 32);
      if (wid == 0)      { if (t > 0)  waitge(HFA, (u32)t); }        // h(t-1)
      else if (wid == 1) { if (t >= 2) waitge(HF1, (u32)(t - 1)); }  // hA overwrite bp
      __syncthreads();
      s16x8 a[16];
      const u16* hr = hA + (size_t)((t + 1) & 1) * 32768 + (size_t)arow * 512 + acol;
      #pragma unroll
      for (int kk = 0; kk < 16; ++kk) ldg16_coh(a[kk], hr + kk * 32);
      #pragma unroll
      for (int kk = 0; kk < 8; ++kk)
        #pragma unroll
        for (int nt = 0; nt < 4; ++nt)
          acc[nt] = __builtin_amdgcn_mfma_f32_16x16x32_bf16(xp[kk], wl[(kk * 4 + nt) * 64 + lane], acc[nt], 0, 0, 0);
      vm_wait();
      #pragma unroll
      for (int kk = 0; kk < 16; ++kk)
        #pragma unroll
        for (int nt = 0; nt < 4; ++nt)
          acc[nt] = __builtin_amdgcn_mfma_f32_16x16x32_bf16(a[kk], wl[((8 + kk) * 4 + nt) * 64 + lane], acc[nt], 0, 0, 0);
    } else {
      if (wid == 0) { if (t > 0) waitge(HF1, (u32)t); }              // own hB(t-1)
      __syncthreads();
      s16x8 a[16];
      const u16* hbr = hB + (size_t)((t + 1) & 1) * 32768 + (size_t)arow * 512 + acol;
      #pragma unroll
      for (int kk = 0; kk < 16; ++kk) ldg16_coh(a[kk], hbr + kk * 32);
      vm_wait();
      #pragma unroll
      for (int kk = 0; kk < 16; ++kk)
        #pragma unroll
        for (int nt = 0; nt < 4; ++nt)
          acc[nt] = __builtin_amdgcn_mfma_f32_16x16x32_bf16(a[kk], wl[((16 + kk) * 4 + nt) * 64 + lane], acc[nt], 0, 0, 0);
      if (wid == 0) waitge(HFA, (u32)(t + 1));                        // fresh hA(t)
      __syncthreads();
      const u16* har = hA + (size_t)(t & 1) * 32768 + (size_t)arow * 512 + acol;
      #pragma unroll
      for (int kk = 0; kk < 16; ++kk) ldg16_coh(a[kk], har + kk * 32);
      vm_wait();
      #pragma unroll
      for (int kk = 0; kk < 16; ++kk)
        #pragma unroll
        for (int nt = 0; nt < 4; ++nt)
          acc[nt] = __builtin_amdgcn_mfma_f32_16x16x32_bf16(a[kk], wl[(kk * 4 + nt) * 64 + lane], acc[nt], 0, 0, 0);
    }

    // D layout: col = lane&15, row = (lane>>4)*4 + r  [m89]; gate = nt
    #pragma unroll
    for (int nt = 0; nt < 4; ++nt) {
      const int brow = wid * 16 + ((lane >> 4) << 2);
      #pragma unroll
      for (int r = 0; r < 4; ++r)
        gates[(nt * 64 + brow + r) * 17 + (lane & 15)] = acc[nt][r];
    }
    __syncthreads();

    // ------------- elementwise (4 cells/thread: rows rg*4+k, col jl)
    float cc[4], oo[4], sv[4], qv[4];
    #pragma unroll
    for (int k = 0; k < 4; ++k) {
      const int row = rg * 4 + k;
      const float gi = gates[(0 * 64 + row) * 17 + jl] + bi;
      const float gf = gates[(1 * 64 + row) * 17 + jl] + bf_;
      const float go = gates[(2 * 64 + row) * 17 + jl] + bo;
      const float gc = gates[(3 * 64 + row) * 17 + jl] + bc;
      const float iv = 1.f / (1.f + __expf(-gi));
      const float fv = 1.f / (1.f + __expf(-gf));
      oo[k] = 1.f / (1.f + __expf(-go));
      const float cn = iv * tanhf(gc) + fv * cst[k];
      cst[k] = cn; cc[k] = cn;
      sv[k] = cn; qv[k] = cn * cn;
    }
    #pragma unroll
    for (int m = 1; m <= 8; m <<= 1)
      #pragma unroll
      for (int k = 0; k < 4; ++k) { sv[k] += __shfl_xor(sv[k], m); qv[k] += __shfl_xor(qv[k], m); }
    if (jl == 0) {
      #pragma unroll
      for (int k = 0; k < 4; ++k) {
        const int row = rg * 4 + k;
        const float qs = (t & 1) ? -qv[k] : qv[k];      // parity in signbit
        stg8_coh(statT + ((size_t)row * 32 + ns) * 2, sv[k], qs);
      }
    }

    // ------------- stats poll: wave w polls exactly rows 16w..16w+15
    {
      const int prow = wid * 16 + (lane >> 2);
      const float* pb = statT + ((size_t)prow * 32 + (size_t)(lane & 3) * 8) * 2;
      const u32 want = (u32)(t & 1);
      f32x2 e[8];
      while (true) {
        #pragma unroll
        for (int j = 0; j < 8; ++j) ldg8f_coh(e[j], pb + j * 2);
        vm_wait();
        u32 ok = 1;
        #pragma unroll
        for (int j = 0; j < 8; ++j) ok &= ((__float_as_uint(e[j][1]) >> 31) == want);
        if (__all((int)ok)) break;
        __builtin_amdgcn_s_sleep(1);
      }
      float ss = 0.f, qq = 0.f;
      #pragma unroll
      for (int j = 0; j < 8; ++j) { ss += e[j][0]; qq += __builtin_fabsf(e[j][1]); }
      ss += __shfl_xor(ss, 1); qq += __shfl_xor(qq, 1);
      ss += __shfl_xor(ss, 2); qq += __shfl_xor(qq, 2);
      if ((lane & 3) == 0) {
        const float mu = ss * (1.f / 512.f);
        const float ms = qq * (1.f / 512.f);
        mus[prow * 2] = mu;
        mus[prow * 2 + 1] = rsqrtf(ms - mu * mu + 1e-5f);
      }
    }
    // wave-local mus (same wave wrote the rows it reads) — no barrier needed

    // ------------- h compute (regs) + LDS stage (R12: coalesced publish)
    float hvv[4];
    #pragma unroll
    for (int k = 0; k < 4; ++k) {
      const int row = rg * 4 + k;
      const float mu = mus[row * 2], rs = mus[row * 2 + 1];
      hvv[k] = oo[k] * tanhf((cc[k] - mu) * rs * gm + bt);
      hst[row * 16 + jl] = f2bf(hvv[k]);
    }
    __syncthreads();
    {
      const int row = tid >> 2, q = tid & 3;
      const u64 v = *(const u64*)(hst + row * 16 + q * 4);
      u16* hd = (ROLE ? hB : hA) + (size_t)(t & 1) * 32768;
      stg8u_coh(hd + (size_t)row * 512 + ns * 16 + q * 4, v);
    }
    vm_wait();
    __syncthreads();
    if (tid == 0)
      __hip_atomic_store(&HF[ns], (u32)(t + 1), __ATOMIC_RELAXED, __HIP_MEMORY_SCOPE_AGENT);

    // ------------- deferred out / finals (plain stores, off the drain path)
    if (ROLE == 1) {
      #pragma unroll
      for (int k = 0; k < 4; ++k)
        out[((size_t)t * 64 + rg * 4 + k) * 512 + jg] = hvv[k];
    }
    if (t == kSeq - 1) {
      #pragma unroll
      for (int k = 0; k < 4; ++k) {
        const int row = rg * 4 + k;
        out[OUT_HFIN + (size_t)ROLE * 32768 + (size_t)row * 512 + jg] = hvv[k];
        out[OUT_CFIN + (size_t)ROLE * 32768 + (size_t)row * 512 + jg] = cc[k];
      }
    }
  }
}

// ---------------------------------------------------------------- persistent
__global__ __launch_bounds__(256, 1) void lstm_persist(
    const u16* __restrict__ xbf, const u16* __restrict__ w0s, const u16* __restrict__ w1s,
    char* ws,
    const float* __restrict__ b0, const float* __restrict__ lg0, const float* __restrict__ lb0,
    const float* __restrict__ b1, const float* __restrict__ lg1, const float* __restrict__ lb1,
    const float* __restrict__ c0in, float* __restrict__ out)
{
  extern __shared__ char smem[];
  const int bid = blockIdx.x;
  u32*   flags = (u32*)(ws + OF_FLAGS);
  u16*   hA    = (u16*)(ws + OF_HA);
  u16*   hB    = (u16*)(ws + OF_HB);
  float* st0   = (float*)(ws + OF_STAT0);
  float* st1   = (float*)(ws + OF_STAT1);

  if (bid < 32)
    team_loop<0>(bid, smem, xbf, w0s, hA, hB, st0, flags, b0, lg0, lb0, c0in, out);
  else
    team_loop<1>(bid - 32, smem, xbf, w1s, hA, hB, st1, flags, b1, lg1, lb1, c0in, out);
}

// ---------------------------------------------------------------- launch
extern "C" void kernel_launch(void* const* d_in, const int* in_sizes, int n_in,
                              void* d_out, int out_size, void* d_ws, size_t ws_size,
                              hipStream_t stream) {
  (void)in_sizes; (void)n_in; (void)out_size;
  const float* x   = (const float*)d_in[0];
  const float* h0  = (const float*)d_in[1];
  const float* c0  = (const float*)d_in[2];
  const float* W0  = (const float*)d_in[3];
  const float* b0  = (const float*)d_in[4];
  const float* g0  = (const float*)d_in[5];
  const float* be0 = (const float*)d_in[6];
  const float* W1  = (const float*)d_in[7];
  const float* b1  = (const float*)d_in[8];
  const float* g1  = (const float*)d_in[9];
  const float* be1 = (const float*)d_in[10];
  float* out = (float*)d_out;

  if (ws_size < WS_NEED) return;   // fail loudly (output stays poisoned)

  char* ws = (char*)d_ws;
  u16* w0s = (u16*)(ws + OF_W0S);
  u16* w1s = (u16*)(ws + OF_W1S);
  u16* xbf = (u16*)(ws + OF_XBF);

  hipLaunchKernelGGL(conv_x_k, dim3(2048), dim3(256), 0, stream,
                     x, xbf, (size_t)kSeq * 64 * 256);
  hipLaunchKernelGGL(conv_w_k, dim3(6144), dim3(256), 0, stream, W0, w0s, 24, 768);
  hipLaunchKernelGGL(conv_w_k, dim3(8192), dim3(256), 0, stream, W1, w1s, 32, 1024);
  hipLaunchKernelGGL(init_k,   dim3(128),  dim3(256), 0, stream, ws, h0);
  hipLaunchKernelGGL(lstm_persist, dim3(64), dim3(256), 151040, stream,
                     xbf, w0s, w1s, ws,
                     b0, g0, be0, b1, g1, be1, c0, out);
}

// Round 13
// 16256.157 us; speedup vs baseline: 2.3135x; 1.0017x over previous
//
#include <hip/hip_runtime.h>

// ----------------------------------------------------------------------------
// 2-layer LayerNorm-LSTM, SEQ=1024, B=64, IN=256, H=512.
// WORKER PART = ROUND-12 BYTE-IDENTICAL (passing, 16.3ms):
//   64 persistent WGs (bid 0..31 layer-0, 32..63 layer-1), 16 hidden cols/WG,
//   weights LDS-resident, fused MFMA+EW+LN, R5-proven sync (sc0sc1 h loads +
//   dense u32 flags; sign-parity self-validating LN stats), coalesced 8B
//   h-publish, deferred out-writes.
// R13 EXPERIMENT: +192 HEATER WGs (bids 64..255) running dependent v_fma
// chains until all 64 worker WGs bump a done counter. Hypothesis: all prior
// designs idle the chip (VALUBusy 2%) -> DPM downclocks several-fold ->
// invariant ~15.5-17us/step regardless of structure. Heaters pin chip-wide
// activity -> clocks stay at 2.4GHz. Workers never wait on heaters (no new
// deadlock channel); heater exit is deterministic (monotone counter).
// ----------------------------------------------------------------------------

typedef short  s16x8 __attribute__((ext_vector_type(8)));
typedef float  f32x4 __attribute__((ext_vector_type(4)));
typedef float  f32x2 __attribute__((ext_vector_type(2)));
typedef unsigned short u16;
typedef unsigned int   u32;
typedef unsigned long long u64;

constexpr int kSeq = 1024;

// ws layout (bytes)
constexpr size_t OF_FLAGS = 0;            // u32[256]: HFA[0..31] HF1[32..63] done[128]
constexpr size_t OF_STAT0 = 1024;         // [64 rows][32 prod] float2 = 16384
constexpr size_t OF_STAT1 = 17408;        // 16384
constexpr size_t OF_HA    = 33792;        // [2 parity][64][512] u16 = 131072
constexpr size_t OF_HB    = 164864;       // 131072
constexpr size_t OF_W0S   = 295936;       // 32*24*4*64*8 u16 = 3145728
constexpr size_t OF_W1S   = 3441664;      // 32*32*4*64*8 u16 = 4194304
constexpr size_t OF_XBF   = 7635968;      // 1024*64*256 u16 = 33554432
constexpr size_t WS_NEED  = OF_XBF + 33554432;

constexpr size_t OUT_HFIN = (size_t)kSeq * 64 * 512;
constexpr size_t OUT_CFIN = OUT_HFIN + 2 * 64 * 512;

__device__ __forceinline__ u16 f2bf(float f) {
  u32 u = __float_as_uint(f);
  return (u16)((u + 0x7fffu + ((u >> 16) & 1u)) >> 16);  // RNE; finite inputs
}

// ---------------- LLC-coherent (sc0 sc1) access helpers ---------------------
__device__ __forceinline__ void ldg16_coh(s16x8& d, const void* p) {
  asm volatile("global_load_dwordx4 %0, %1, off sc0 sc1" : "=v"(d) : "v"(p) : "memory");
}
__device__ __forceinline__ void ldg8f_coh(f32x2& d, const void* p) {
  asm volatile("global_load_dwordx2 %0, %1, off sc0 sc1" : "=v"(d) : "v"(p) : "memory");
}
__device__ __forceinline__ void stg8_coh(float* p, float a, float b) {
  f32x2 t; t[0] = a; t[1] = b;
  asm volatile("global_store_dwordx2 %0, %1, off sc0 sc1" :: "v"(p), "v"(t) : "memory");
}
__device__ __forceinline__ void stg8u_coh(u16* p, u64 v) {
  asm volatile("global_store_dwordx2 %0, %1, off sc0 sc1" :: "v"(p), "v"(v) : "memory");
}
__device__ __forceinline__ void vm_wait() {
  asm volatile("s_waitcnt vmcnt(0)" ::: "memory");
  __builtin_amdgcn_sched_barrier(0);     // rule 18: nothing crosses the wait
}
// Spin until all 32 flags >= tgt (all 64 lanes read flags[lane&31]).
__device__ __forceinline__ void waitge(u32* f, u32 tgt) {
  const int l = threadIdx.x & 31;
  while (true) {
    u32 v = __hip_atomic_load(&f[l], __ATOMIC_RELAXED, __HIP_MEMORY_SCOPE_AGENT);
    if (__all((int)(v >= tgt))) break;
    __builtin_amdgcn_s_sleep(2);
  }
}

// ---------------------------------------------------------------- conversions
__global__ void conv_x_k(const float* __restrict__ x, u16* __restrict__ xd, size_t n) {
  size_t i = (size_t)blockIdx.x * blockDim.x + threadIdx.x;
  size_t st = (size_t)gridDim.x * blockDim.x;
  for (; i < n; i += st) xd[i] = f2bf(x[i]);
}

// W [2048][Kdim] -> [ns(32)][kst(KST)][nt(4)][lane(64)][e(8)]
// n_orig = nt*512 + ns*16 + (lane&15); k = kst*32 + (lane>>4)*8 + e
__global__ void conv_w_k(const float* __restrict__ W, u16* __restrict__ Wd,
                         int KST, int Kdim) {
  int i = blockIdx.x * blockDim.x + threadIdx.x;
  if (i >= 32 * KST * 2048) return;
  int e = i & 7, lane = (i >> 3) & 63, nt = (i >> 9) & 3;
  int r = i >> 11;
  int kst = r % KST, ns = r / KST;
  int n_orig = nt * 512 + ns * 16 + (lane & 15);
  int k = kst * 32 + ((lane >> 4) << 3) + e;
  Wd[i] = f2bf(W[(size_t)n_orig * Kdim + k]);
}

__global__ void init_k(char* ws, const float* __restrict__ h0) {
  int i = blockIdx.x * blockDim.x + threadIdx.x;   // 0..32767
  u32* f = (u32*)ws;
  if (i < 256) f[i] = 0u;                          // flags + done counter
  if (i < 4096) {       // stats entries -> (s=0, q=-0.0): signbit 1 != (t=0)&1
    ((u64*)(ws + OF_STAT0))[i] = 0x8000000000000000ull;
    ((u64*)(ws + OF_STAT1))[i] = 0x8000000000000000ull;
  }
  // parity-1 buffers <- initial hidden states
  ((u16*)(ws + OF_HA))[32768 + i] = f2bf(h0[i]);
  ((u16*)(ws + OF_HB))[32768 + i] = f2bf(h0[32768 + i]);
}

// ---------------------------------------------------------------- team loop
template <int ROLE>
__device__ __forceinline__ void team_loop(
    int ns, char* smem,
    const u16* __restrict__ xbf, const u16* __restrict__ wsw,
    u16* hA, u16* hB, float* statT, u32* flags,
    const float* __restrict__ bias, const float* __restrict__ gam_,
    const float* __restrict__ bet_, const float* __restrict__ c0in,
    float* __restrict__ out)
{
  constexpr int KST = ROLE ? 32 : 24;     // K/32
  const int tid = threadIdx.x;
  const int lane = tid & 63, wid = tid >> 6;
  const int arow = wid * 16 + (lane & 15);        // batch row of A-frag
  const int acol = (lane >> 4) << 3;              // K offset within 32
  const int jl = tid & 15, rg = tid >> 4;         // EW col-in-16, row-group
  const int jg = ns * 16 + jl;                    // owned hidden column

  u32* HFA = flags;
  u32* HF1 = flags + 32;
  u32* HF  = ROLE ? HF1 : HFA;

  s16x8* wl    = (s16x8*)smem;                    // KST*4 KB weights
  float* gates = (float*)(smem + (size_t)KST * 4096);          // [4][64][17] f32
  float* mus   = (float*)(smem + (size_t)KST * 4096 + 17408);  // [64][2]
  u16*   hst   = (u16*)(smem + (size_t)KST * 4096 + 17920);    // [64][16] u16

  // weights fully into LDS
  const s16x8* wsrc = (const s16x8*)wsw + (size_t)ns * KST * 256;
  for (int i = tid; i < KST * 256; i += 256) wl[i] = wsrc[i];

  const float bi = bias[jg], bf_ = bias[512 + jg], bo = bias[1024 + jg], bc = bias[1536 + jg];
  const float gm = gam_[jg], bt = bet_[jg];
  float cst[4];
  #pragma unroll
  for (int k = 0; k < 4; ++k)
    cst[k] = c0in[(size_t)(ROLE * 64 + rg * 4 + k) * 512 + jg];
  __syncthreads();

  for (int t = 0; t < kSeq; ++t) {
    f32x4 acc[4];
    #pragma unroll
    for (int nt = 0; nt < 4; ++nt) acc[nt] = (f32x4){0.f, 0.f, 0.f, 0.f};

    // ------------- matmul: gates[64b][64 gatecols] = act(t) @ W^T
    if (ROLE == 0) {
      s16x8 xp[8];
      const u16* xr = xbf + ((size_t)t * 64 + arow) * 256 + acol;
      #pragma unroll
      for (int kk = 0; kk < 8; ++kk) xp[kk] = *(const s16x8*)(xr + kk * 32);
      if (wid == 0)      { if (t > 0)  waitge(HFA, (u32)t); }        // h(t-1)
      else if (wid == 1) { if (t >= 2) waitge(HF1, (u32)(t - 1)); }  // hA overwrite bp
      __syncthreads();
      s16x8 a[16];
      const u16* hr = hA + (size_t)((t + 1) & 1) * 32768 + (size_t)arow * 512 + acol;
      #pragma unroll
      for (int kk = 0; kk < 16; ++kk) ldg16_coh(a[kk], hr + kk * 32);
      #pragma unroll
      for (int kk = 0; kk < 8; ++kk)
        #pragma unroll
        for (int nt = 0; nt < 4; ++nt)
          acc[nt] = __builtin_amdgcn_mfma_f32_16x16x32_bf16(xp[kk], wl[(kk * 4 + nt) * 64 + lane], acc[nt], 0, 0, 0);
      vm_wait();
      #pragma unroll
      for (int kk = 0; kk < 16; ++kk)
        #pragma unroll
        for (int nt = 0; nt < 4; ++nt)
          acc[nt] = __builtin_amdgcn_mfma_f32_16x16x32_bf16(a[kk], wl[((8 + kk) * 4 + nt) * 64 + lane], acc[nt], 0, 0, 0);
    } else {
      if (wid == 0) { if (t > 0) waitge(HF1, (u32)t); }              // own hB(t-1)
      __syncthreads();
      s16x8 a[16];
      const u16* hbr = hB + (size_t)((t + 1) & 1) * 32768 + (size_t)arow * 512 + acol;
      #pragma unroll
      for (int kk = 0; kk < 16; ++kk) ldg16_coh(a[kk], hbr + kk * 32);
      vm_wait();
      #pragma unroll
      for (int kk = 0; kk < 16; ++kk)
        #pragma unroll
        for (int nt = 0; nt < 4; ++nt)
          acc[nt] = __builtin_amdgcn_mfma_f32_16x16x32_bf16(a[kk], wl[((16 + kk) * 4 + nt) * 64 + lane], acc[nt], 0, 0, 0);
      if (wid == 0) waitge(HFA, (u32)(t + 1));                        // fresh hA(t)
      __syncthreads();
      const u16* har = hA + (size_t)(t & 1) * 32768 + (size_t)arow * 512 + acol;
      #pragma unroll
      for (int kk = 0; kk < 16; ++kk) ldg16_coh(a[kk], har + kk * 32);
      vm_wait();
      #pragma unroll
      for (int kk = 0; kk < 16; ++kk)
        #pragma unroll
        for (int nt = 0; nt < 4; ++nt)
          acc[nt] = __builtin_amdgcn_mfma_f32_16x16x32_bf16(a[kk], wl[(kk * 4 + nt) * 64 + lane], acc[nt], 0, 0, 0);
    }

    // D layout: col = lane&15, row = (lane>>4)*4 + r  [m89]; gate = nt
    #pragma unroll
    for (int nt = 0; nt < 4; ++nt) {
      const int brow = wid * 16 + ((lane >> 4) << 2);
      #pragma unroll
      for (int r = 0; r < 4; ++r)
        gates[(nt * 64 + brow + r) * 17 + (lane & 15)] = acc[nt][r];
    }
    __syncthreads();

    // ------------- elementwise (4 cells/thread: rows rg*4+k, col jl)
    float cc[4], oo[4], sv[4], qv[4];
    #pragma unroll
    for (int k = 0; k < 4; ++k) {
      const int row = rg * 4 + k;
      const float gi = gates[(0 * 64 + row) * 17 + jl] + bi;
      const float gf = gates[(1 * 64 + row) * 17 + jl] + bf_;
      const float go = gates[(2 * 64 + row) * 17 + jl] + bo;
      const float gc = gates[(3 * 64 + row) * 17 + jl] + bc;
      const float iv = 1.f / (1.f + __expf(-gi));
      const float fv = 1.f / (1.f + __expf(-gf));
      oo[k] = 1.f / (1.f + __expf(-go));
      const float cn = iv * tanhf(gc) + fv * cst[k];
      cst[k] = cn; cc[k] = cn;
      sv[k] = cn; qv[k] = cn * cn;
    }
    #pragma unroll
    for (int m = 1; m <= 8; m <<= 1)
      #pragma unroll
      for (int k = 0; k < 4; ++k) { sv[k] += __shfl_xor(sv[k], m); qv[k] += __shfl_xor(qv[k], m); }
    if (jl == 0) {
      #pragma unroll
      for (int k = 0; k < 4; ++k) {
        const int row = rg * 4 + k;
        const float qs = (t & 1) ? -qv[k] : qv[k];      // parity in signbit
        stg8_coh(statT + ((size_t)row * 32 + ns) * 2, sv[k], qs);
      }
    }

    // ------------- stats poll: wave w polls exactly rows 16w..16w+15
    {
      const int prow = wid * 16 + (lane >> 2);
      const float* pb = statT + ((size_t)prow * 32 + (size_t)(lane & 3) * 8) * 2;
      const u32 want = (u32)(t & 1);
      f32x2 e[8];
      while (true) {
        #pragma unroll
        for (int j = 0; j < 8; ++j) ldg8f_coh(e[j], pb + j * 2);
        vm_wait();
        u32 ok = 1;
        #pragma unroll
        for (int j = 0; j < 8; ++j) ok &= ((__float_as_uint(e[j][1]) >> 31) == want);
        if (__all((int)ok)) break;
        __builtin_amdgcn_s_sleep(1);
      }
      float ss = 0.f, qq = 0.f;
      #pragma unroll
      for (int j = 0; j < 8; ++j) { ss += e[j][0]; qq += __builtin_fabsf(e[j][1]); }
      ss += __shfl_xor(ss, 1); qq += __shfl_xor(qq, 1);
      ss += __shfl_xor(ss, 2); qq += __shfl_xor(qq, 2);
      if ((lane & 3) == 0) {
        const float mu = ss * (1.f / 512.f);
        const float ms = qq * (1.f / 512.f);
        mus[prow * 2] = mu;
        mus[prow * 2 + 1] = rsqrtf(ms - mu * mu + 1e-5f);
      }
    }
    // wave-local mus (same wave wrote the rows it reads) — no barrier needed

    // ------------- h compute (regs) + LDS stage (coalesced publish)
    float hvv[4];
    #pragma unroll
    for (int k = 0; k < 4; ++k) {
      const int row = rg * 4 + k;
      const float mu = mus[row * 2], rs = mus[row * 2 + 1];
      hvv[k] = oo[k] * tanhf((cc[k] - mu) * rs * gm + bt);
      hst[row * 16 + jl] = f2bf(hvv[k]);
    }
    __syncthreads();
    {
      const int row = tid >> 2, q = tid & 3;
      const u64 v = *(const u64*)(hst + row * 16 + q * 4);
      u16* hd = (ROLE ? hB : hA) + (size_t)(t & 1) * 32768;
      stg8u_coh(hd + (size_t)row * 512 + ns * 16 + q * 4, v);
    }
    vm_wait();
    __syncthreads();
    if (tid == 0)
      __hip_atomic_store(&HF[ns], (u32)(t + 1), __ATOMIC_RELAXED, __HIP_MEMORY_SCOPE_AGENT);

    // ------------- deferred out / finals (plain stores, off the drain path)
    if (ROLE == 1) {
      #pragma unroll
      for (int k = 0; k < 4; ++k)
        out[((size_t)t * 64 + rg * 4 + k) * 512 + jg] = hvv[k];
    }
    if (t == kSeq - 1) {
      #pragma unroll
      for (int k = 0; k < 4; ++k) {
        const int row = rg * 4 + k;
        out[OUT_HFIN + (size_t)ROLE * 32768 + (size_t)row * 512 + jg] = hvv[k];
        out[OUT_CFIN + (size_t)ROLE * 32768 + (size_t)row * 512 + jg] = cc[k];
      }
    }
  }
}

// ---------------------------------------------------------------- persistent
__global__ __launch_bounds__(256, 1) void lstm_persist(
    const u16* __restrict__ xbf, const u16* __restrict__ w0s, const u16* __restrict__ w1s,
    char* ws,
    const float* __restrict__ b0, const float* __restrict__ lg0, const float* __restrict__ lb0,
    const float* __restrict__ b1, const float* __restrict__ lg1, const float* __restrict__ lb1,
    const float* __restrict__ c0in, float* __restrict__ out)
{
  extern __shared__ char smem[];
  const int bid = blockIdx.x;
  u32*   flags = (u32*)(ws + OF_FLAGS);
  u16*   hA    = (u16*)(ws + OF_HA);
  u16*   hB    = (u16*)(ws + OF_HB);
  float* st0   = (float*)(ws + OF_STAT0);
  float* st1   = (float*)(ws + OF_STAT1);
  u32*   done  = flags + 128;

  if (bid < 32) {
    team_loop<0>(bid, smem, xbf, w0s, hA, hB, st0, flags, b0, lg0, lb0, c0in, out);
  } else if (bid < 64) {
    team_loop<1>(bid - 32, smem, xbf, w1s, hA, hB, st1, flags, b1, lg1, lb1, c0in, out);
  } else {
    // ---------------- HEATER: pin chip activity (DPM clock experiment) ------
    float a = 1.000001f;
    const float b = 0.999999f, c = 1e-7f;
    while (true) {
      #pragma unroll 16
      for (int i = 0; i < 2048; ++i)
        asm volatile("v_fma_f32 %0, %0, %1, %2" : "+v"(a) : "v"(b), "v"(c));
      u32 d = __hip_atomic_load(done, __ATOMIC_RELAXED, __HIP_MEMORY_SCOPE_AGENT);
      if (d >= 64u) break;
    }
    asm volatile("" :: "v"(a));   // keep the chain live
    return;
  }
  // worker WGs signal completion (heaters exit when all 64 have signaled)
  __syncthreads();
  if (threadIdx.x == 0)
    __hip_atomic_fetch_add(done, 1u, __ATOMIC_RELAXED, __HIP_MEMORY_SCOPE_AGENT);
}

// ---------------------------------------------------------------- launch
extern "C" void kernel_launch(void* const* d_in, const int* in_sizes, int n_in,
                              void* d_out, int out_size, void* d_ws, size_t ws_size,
                              hipStream_t stream) {
  (void)in_sizes; (void)n_in; (void)out_size;
  const float* x   = (const float*)d_in[0];
  const float* h0  = (const float*)d_in[1];
  const float* c0  = (const float*)d_in[2];
  const float* W0  = (const float*)d_in[3];
  const float* b0  = (const float*)d_in[4];
  const float* g0  = (const float*)d_in[5];
  const float* be0 = (const float*)d_in[6];
  const float* W1  = (const float*)d_in[7];
  const float* b1  = (const float*)d_in[8];
  const float* g1  = (const float*)d_in[9];
  const float* be1 = (const float*)d_in[10];
  float* out = (float*)d_out;

  if (ws_size < WS_NEED) return;   // fail loudly (output stays poisoned)

  char* ws = (char*)d_ws;
  u16* w0s = (u16*)(ws + OF_W0S);
  u16* w1s = (u16*)(ws + OF_W1S);
  u16* xbf = (u16*)(ws + OF_XBF);

  hipLaunchKernelGGL(conv_x_k, dim3(2048), dim3(256), 0, stream,
                     x, xbf, (size_t)kSeq * 64 * 256);
  hipLaunchKernelGGL(conv_w_k, dim3(6144), dim3(256), 0, stream, W0, w0s, 24, 768);
  hipLaunchKernelGGL(conv_w_k, dim3(8192), dim3(256), 0, stream, W1, w1s, 32, 1024);
  hipLaunchKernelGGL(init_k,   dim3(128),  dim3(256), 0, stream, ws, h0);
  hipLaunchKernelGGL(lstm_persist, dim3(256), dim3(256), 151040, stream,
                     xbf, w0s, w1s, ws,
                     b0, g0, be0, b1, g1, be1, c0, out);
}